// Round 6
// baseline (254.127 us; speedup 1.0000x reference)
//
#include <hip/hip_runtime.h>

// MQA: B=2, S=2048, HID=2048, H=16, D=128 (single KV head), causal.
// Pipeline: cast -> fused QKV NT-GEMM (bf16 MFMA) -> V transpose -> kmax ->
//           flash attention (4 waves x 128 contig q-rows, 512 blocks heavy-
//           first, 2 blocks/CU, dbuf swizzled LDS KV, Cauchy softmax) -> GEMM.

#define S_LEN 2048
#define HID_  2048
#define D_    128
#define NQKV  2304   // 2048 Q + 128 K + 128 V columns

typedef __attribute__((ext_vector_type(8))) short bf16x8;
typedef __attribute__((ext_vector_type(4))) short s16x4;
typedef __attribute__((ext_vector_type(4))) float f32x4;

__device__ __forceinline__ unsigned short f2b(float f) {
  union { float f; unsigned int u; } a; a.f = f;
  unsigned int u = a.u;
  return (unsigned short)((u + 0x7fffu + ((u >> 16) & 1u)) >> 16);  // RNE
}

__device__ __forceinline__ float b2f(unsigned short s) {
  union { unsigned int u; float f; } a; a.u = ((unsigned int)s) << 16;
  return a.f;
}

__device__ __forceinline__ void load_lds16(const void* g, void* l) {
  __builtin_amdgcn_global_load_lds(
      (const __attribute__((address_space(1))) void*)g,
      (__attribute__((address_space(3))) void*)l, 16, 0, 0);
}

__device__ __forceinline__ f32x4 mfma16(bf16x8 a, bf16x8 b, f32x4 c) {
  return __builtin_amdgcn_mfma_f32_16x16x32_bf16(a, b, c, 0, 0, 0);
}

// ---------------- casts / packing ----------------

__global__ void cast_f32_bf16_k(const float* __restrict__ in,
                                unsigned short* __restrict__ out, int n4) {
  const int idx = blockIdx.x * 256 + threadIdx.x;
  if (idx < n4) {
    const float4 v = ((const float4*)in)[idx];
    ushort4 o;
    o.x = f2b(v.x); o.y = f2b(v.y); o.z = f2b(v.z); o.w = f2b(v.w);
    ((ushort4*)out)[idx] = o;
  }
}

__global__ void build_wcat_k(const float* __restrict__ Wq,
                             const float* __restrict__ Wk,
                             const float* __restrict__ Wv,
                             const float* __restrict__ bq,
                             const float* __restrict__ bk,
                             const float* __restrict__ bv,
                             unsigned short* __restrict__ Wcat,
                             float* __restrict__ bcat,
                             float* __restrict__ Kmax) {
  const int idx = blockIdx.x * 256 + threadIdx.x;
  const int i = idx * 4;
  const int row = i >> 11;
  const int col = i & 2047;
  const float* src;
  if (row < 2048)      src = Wq + (size_t)row * 2048 + col;
  else if (row < 2176) src = Wk + (size_t)(row - 2048) * 2048 + col;
  else                 src = Wv + (size_t)(row - 2176) * 2048 + col;
  const float4 v = *(const float4*)src;
  ushort4 o;
  o.x = f2b(v.x); o.y = f2b(v.y); o.z = f2b(v.z); o.w = f2b(v.w);
  *(ushort4*)(Wcat + i) = o;
  if (idx < NQKV)
    bcat[idx] = (idx < 2048) ? bq[idx] : (idx < 2176) ? bk[idx - 2048] : bv[idx - 2176];
  if (idx < 2) Kmax[idx] = 0.f;   // re-init every launch (runs before kmax_k)
}

// Vt[b][d][s] = QKV[b*S+s][2176+d] -- LDS-tiled transpose
__global__ __launch_bounds__(256)
void transpose_v(const unsigned short* __restrict__ QKV,
                 unsigned short* __restrict__ Vt) {
  __shared__ unsigned short tile[64][136];
  const int tid = threadIdx.x;
  const int s0  = blockIdx.x * 64;
  const int b   = blockIdx.y;
  const int row = tid >> 2;
  const int cb  = (tid & 3) * 32;
  const unsigned short* src = QKV + (size_t)(b * S_LEN + s0 + row) * NQKV + 2176 + cb;
#pragma unroll
  for (int i = 0; i < 4; ++i)
    *(bf16x8*)&tile[row][cb + i * 8] = *(const bf16x8*)(src + i * 8);
  __syncthreads();
  const int d  = tid >> 1;
  const int sc = (tid & 1) * 32;
  unsigned short* dst = Vt + ((size_t)b * D_ + d) * S_LEN + s0 + sc;
#pragma unroll
  for (int i = 0; i < 4; ++i) {
    bf16x8 vv;
#pragma unroll
    for (int e = 0; e < 8; ++e) vv[e] = tile[sc + i * 8 + e][d];
    *(bf16x8*)(dst + i * 8) = vv;
  }
}

// max_s ||k[b,s]||^2 -> Kmax[b] (as float bits via atomicMax on uint)
__global__ __launch_bounds__(256)
void kmax_k(const unsigned short* __restrict__ QKV, float* __restrict__ Kmax) {
  __shared__ float red[256];
  const int tid = threadIdx.x;
  const int b = blockIdx.x >> 3;
  const int s = (blockIdx.x & 7) * 256 + tid;
  const unsigned short* kp = QKV + (size_t)(b * S_LEN + s) * NQKV + 2048;
  float sum = 0.f;
#pragma unroll
  for (int i = 0; i < 16; ++i) {
    bf16x8 v = *(const bf16x8*)(kp + i * 8);
#pragma unroll
    for (int e = 0; e < 8; ++e) { const float f = b2f((unsigned short)v[e]); sum += f * f; }
  }
  red[tid] = sum;
  __syncthreads();
  for (int off = 128; off > 0; off >>= 1) {
    if (tid < off) red[tid] = fmaxf(red[tid], red[tid + off]);
    __syncthreads();
  }
  if (tid == 0) atomicMax((unsigned int*)(Kmax + b), __float_as_uint(red[0]));
}

// ---------------- NT GEMM (m97 structure, unchanged) ----------------

template <int OUT_F32>
__global__ __launch_bounds__(256)
void gemm_nt(const unsigned short* __restrict__ A,
             const unsigned short* __restrict__ Bm,
             const float* __restrict__ bias,
             void* __restrict__ Cv,
             int M, int N, int K) {
  __shared__ unsigned short As[128 * 32];
  __shared__ unsigned short Bs[128 * 32];
  const int tid  = threadIdx.x;
  const int lane = tid & 63;
  const int wv   = tid >> 6;
  const int wr   = wv >> 1, wc = wv & 1;
  const int g    = lane >> 4, r = lane & 15;
  const int m0   = blockIdx.y * 128;
  const int n0   = blockIdx.x * 128;

  const unsigned short* ga0 = A  + (size_t)(m0 + (tid >> 2)) * K + (tid & 3) * 8;
  const unsigned short* ga1 = ga0 + (size_t)64 * K;
  const unsigned short* gb0 = Bm + (size_t)(n0 + (tid >> 2)) * K + (tid & 3) * 8;
  const unsigned short* gb1 = gb0 + (size_t)64 * K;

  f32x4 acc[4][4] = {};

  for (int k0 = 0; k0 < K; k0 += 32) {
    __syncthreads();
    load_lds16(ga0 + k0, &As[tid * 8]);
    load_lds16(ga1 + k0, &As[2048 + tid * 8]);
    load_lds16(gb0 + k0, &Bs[tid * 8]);
    load_lds16(gb1 + k0, &Bs[2048 + tid * 8]);
    __syncthreads();
    bf16x8 af[4], bfr[4];
#pragma unroll
    for (int i = 0; i < 4; ++i)
      af[i] = *(const bf16x8*)&As[(wr * 64 + i * 16 + r) * 32 + g * 8];
#pragma unroll
    for (int i = 0; i < 4; ++i)
      bfr[i] = *(const bf16x8*)&Bs[(wc * 64 + i * 16 + r) * 32 + g * 8];
#pragma unroll
    for (int i = 0; i < 4; ++i)
#pragma unroll
      for (int j = 0; j < 4; ++j)
        acc[i][j] = mfma16(af[i], bfr[j], acc[i][j]);
  }

#pragma unroll
  for (int i = 0; i < 4; ++i) {
    const int row = m0 + wr * 64 + i * 16 + g * 4;
#pragma unroll
    for (int j = 0; j < 4; ++j) {
      const int col = n0 + wc * 64 + j * 16 + r;
      const float bb = bias[col];
#pragma unroll
      for (int e = 0; e < 4; ++e) {
        const float v = acc[i][j][e] + bb;
        if (OUT_F32) ((float*)Cv)[(size_t)(row + e) * N + col] = v;
        else ((unsigned short*)Cv)[(size_t)(row + e) * N + col] = f2b(v);
      }
    }
  }
}

// ---------------- flash attention (causal, MQA) ----------------
// 4 waves x 32 contiguous q-rows = 128 rows/block; grid 16x32 = 512 blocks,
// heavy-first. All waves compute-active in (almost) all tiles; 73.75 KB LDS
// -> 2 blocks/CU co-resident to hide barrier/staging stalls.
// KVBLK=64 double-buffered XOR-swizzled LDS; Cauchy-bound softmax; ones-MFMA
// denominator; single per-wave P buffer reused across strips (in-wave order).

__global__ __launch_bounds__(256, 2)
void mqa_attn(const unsigned short* __restrict__ QKV,
              const unsigned short* __restrict__ Vt,
              const float* __restrict__ Kmax,
              unsigned short* __restrict__ Ob) {
  __shared__ __align__(16) char Ks[2][64 * 256];    // [kv][d] 256B rows, swizzled
  __shared__ __align__(16) char Vs[2][128 * 128];   // [d][kv] 128B rows, swizzled
  __shared__ __align__(16) char Pl[4][2304];        // per-wave P [16q][72kv]

  const int tid  = threadIdx.x;
  const int lane = tid & 63;
  const int wv   = tid >> 6;           // 0..3
  const int g    = lane >> 4;
  const int c    = lane & 15;
  const int qblk = 15 - (blockIdx.x >> 5);   // heavy blocks dispatch first
  const int bh   = blockIdx.x & 31;
  const int b    = bh >> 4;
  const int h    = bh & 15;
  const int qw   = 128 * qblk + 32 * wv;     // wave's 32-row base
  const int nt   = 2 * qblk + 2;             // KV tiles of 64

  char* pw = &Pl[wv][0];

  // Q fragments per strip: lane holds Q[q=qw+16*st+c][d = kk*32 + g*8 + e]
  bf16x8 qf[2][4];
#pragma unroll
  for (int st = 0; st < 2; ++st) {
    const unsigned short* qp =
        QKV + (size_t)(b * S_LEN + qw + 16 * st + c) * NQKV + h * D_ + g * 8;
#pragma unroll
    for (int kk = 0; kk < 4; ++kk) qf[st][kk] = *(const bf16x8*)(qp + kk * 32);
  }

  // Cauchy-Schwarz bound per strip: m0 = sscale*||q||*max||k|| + 1 (exp2 dom)
  const float sscale = 0.08838834764831845f * 1.4426950408889634f;  // scale*log2e
  const float km = sqrtf(Kmax[b]);
  float m0c[2];
#pragma unroll
  for (int st = 0; st < 2; ++st) {
    float qn2 = 0.f;
#pragma unroll
    for (int kk = 0; kk < 4; ++kk)
#pragma unroll
      for (int e = 0; e < 8; ++e) {
        const float qv = b2f((unsigned short)qf[st][kk][e]);
        qn2 += qv * qv;
      }
    qn2 += __shfl_xor(qn2, 16);
    qn2 += __shfl_xor(qn2, 32);
    m0c[st] = sqrtf(qn2) * km * sscale + 1.0f;
  }

  const char* kbc = (const char*)(QKV + (size_t)(b * S_LEN) * NQKV + 2048);
  const char* vbc = (const char*)(Vt + (size_t)b * D_ * S_LEN);

  f32x4 acc[2][8];
#pragma unroll
  for (int st = 0; st < 2; ++st)
#pragma unroll
    for (int i = 0; i < 8; ++i) { acc[st][i][0]=0.f; acc[st][i][1]=0.f; acc[st][i][2]=0.f; acc[st][i][3]=0.f; }
  f32x4 accl[2];
#pragma unroll
  for (int st = 0; st < 2; ++st) { accl[st][0]=0.f; accl[st][1]=0.f; accl[st][2]=0.f; accl[st][3]=0.f; }

  bf16x8 onesf;
#pragma unroll
  for (int e = 0; e < 8; ++e) onesf[e] = (short)0x3F80;  // bf16 1.0

  const int xr = (c & 7) << 4;

  // ---- staging: 1024 chunks K (64x256B) + 1024 chunks V (128x128B), 256 thr ----
#define STAGE(bufi, t)                                                         \
  {                                                                            \
    const int kv0_ = (t) * 64;                                                 \
    _Pragma("unroll")                                                          \
    for (int i_ = 0; i_ < 4; ++i_) {                                           \
      const int ch_ = tid + 256 * i_;                                          \
      const int kr_ = ch_ >> 4;                                                \
      const int kc_ = ((ch_ & 15) << 4) ^ ((kr_ & 7) << 4);                    \
      load_lds16(kbc + (size_t)(kv0_ + kr_) * (NQKV * 2) + kc_,                \
                 Ks[bufi] + ch_ * 16);                                         \
      const int vr_ = ch_ >> 3;                                                \
      const int vc_ = ((ch_ & 7) << 4) ^ ((vr_ & 7) << 4);                     \
      load_lds16(vbc + (size_t)vr_ * (S_LEN * 2) + kv0_ * 2 + vc_,             \
                 Vs[bufi] + ch_ * 16);                                         \
    }                                                                          \
  }

  STAGE(0, 0);
  int cur = 0;

  for (int t = 0; t < nt; ++t) {
    __syncthreads();                       // publishes buf[cur]
    if (t + 1 < nt) STAGE(cur ^ 1, t + 1); // prefetch overlaps compute

    const char* ksb = Ks[cur];
    const char* vsb = Vs[cur];
    const int kv0 = t * 64;
    const int rel0 = qw + 15 - kv0;        // strip0 coverage
    const int rel1 = qw + 31 - kv0;        // strip1 coverage (>= rel0)
    cur ^= 1;
    if (rel1 < 0) continue;                // wave fully past-diagonal (rare)

    // QK^T (swapped): sc[st][m] = K_m * Q_st ; D[row=kv=16m+4g+r][col=q=c]
    f32x4 sc[2][4];
#pragma unroll
    for (int st = 0; st < 2; ++st)
#pragma unroll
      for (int m = 0; m < 4; ++m) { sc[st][m][0]=0.f; sc[st][m][1]=0.f; sc[st][m][2]=0.f; sc[st][m][3]=0.f; }

    __builtin_amdgcn_s_setprio(1);
#pragma unroll
    for (int kk = 0; kk < 4; ++kk) {
      const int cb = (kk * 64 + g * 16) ^ xr;
      bf16x8 kfm[4];
#pragma unroll
      for (int m = 0; m < 4; ++m)
        if (16 * m <= rel1) kfm[m] = *(const bf16x8*)(ksb + c * 256 + m * 4096 + cb);
#pragma unroll
      for (int m = 0; m < 4; ++m) {
        if (16 * m <= rel0) sc[0][m] = mfma16(kfm[m], qf[0][kk], sc[0][m]);
        if (16 * m <= rel1) sc[1][m] = mfma16(kfm[m], qf[1][kk], sc[1][m]);
      }
    }
    __builtin_amdgcn_s_setprio(0);

    // V fragments, shared by both strips (upper half only when needed)
    bf16x8 vf0[8], vf1[8];
#pragma unroll
    for (int nf = 0; nf < 8; ++nf)
      vf0[nf] = *(const bf16x8*)(vsb + (nf * 16 + c) * 128 + ((g * 16) ^ xr));
    if (rel1 >= 32)
#pragma unroll
      for (int nf = 0; nf < 8; ++nf)
        vf1[nf] = *(const bf16x8*)(vsb + (nf * 16 + c) * 128 + ((64 + g * 16) ^ xr));

    // per strip: softmax -> P (single buffer, in-wave DS ordering) -> PV
#pragma unroll
    for (int st = 0; st < 2; ++st) {
      const int rels = st ? rel1 : rel0;
      if (rels < 0) continue;
      const float m0s = m0c[st];
      const int qloc = qw + 16 * st + c;
#pragma unroll
      for (int mi = 0; mi < 4; ++mi) {
        s16x4 pk;
#pragma unroll
        for (int r = 0; r < 4; ++r) {
          const int kva = kv0 + 16 * mi + 4 * g + r;
          float a = sc[st][mi][r] * sscale - m0s;
          a = (kva <= qloc) ? a : -__builtin_inff();
          pk[r] = (short)f2b(__builtin_amdgcn_exp2f(a));
        }
        *(s16x4*)(pw + c * 144 + mi * 32 + g * 8) = pk;
      }
      asm volatile("s_waitcnt lgkmcnt(0)" ::: "memory");
      __builtin_amdgcn_sched_barrier(0);

      const bf16x8 pf0 = *(const bf16x8*)(pw + c * 144 + g * 16);
      __builtin_amdgcn_s_setprio(1);
      accl[st] = mfma16(pf0, onesf, accl[st]);
#pragma unroll
      for (int nf = 0; nf < 8; ++nf) acc[st][nf] = mfma16(pf0, vf0[nf], acc[st][nf]);
      if (rels >= 32) {
        const bf16x8 pf1 = *(const bf16x8*)(pw + c * 144 + 64 + g * 16);
        accl[st] = mfma16(pf1, onesf, accl[st]);
#pragma unroll
        for (int nf = 0; nf < 8; ++nf) acc[st][nf] = mfma16(pf1, vf1[nf], acc[st][nf]);
      }
      __builtin_amdgcn_s_setprio(0);
    }
  }

  // epilogue: normalize, store bf16 [4096][2048]
#pragma unroll
  for (int st = 0; st < 2; ++st) {
    unsigned short* op =
        Ob + (size_t)(b * S_LEN + qw + 16 * st + 4 * g) * HID_ + h * D_ + c;
#pragma unroll
    for (int jj = 0; jj < 4; ++jj) {
      const float inv = 1.0f / accl[st][jj];
#pragma unroll
      for (int nf = 0; nf < 8; ++nf)
        op[(size_t)jj * HID_ + nf * 16] = f2b(acc[st][nf][jj] * inv);
    }
  }
#undef STAGE
}

// ---------------- launcher ----------------

extern "C" void kernel_launch(void* const* d_in, const int* in_sizes, int n_in,
                              void* d_out, int out_size, void* d_ws, size_t ws_size,
                              hipStream_t stream) {
  (void)in_sizes; (void)n_in; (void)out_size; (void)ws_size;
  const float* x  = (const float*)d_in[0];
  const float* Wq = (const float*)d_in[2];
  const float* bq = (const float*)d_in[3];
  const float* Wk = (const float*)d_in[4];
  const float* bk = (const float*)d_in[5];
  const float* Wv = (const float*)d_in[6];
  const float* bv = (const float*)d_in[7];
  const float* Wo = (const float*)d_in[8];
  const float* bo = (const float*)d_in[9];
  float* out = (float*)d_out;

  char* p = (char*)d_ws;
  unsigned short* xb   = (unsigned short*)p;  p += (size_t)4096 * 2048 * 2;
  unsigned short* Wcat = (unsigned short*)p;  p += (size_t)2304 * 2048 * 2;
  float*          bcat = (float*)p;           p += 16384;
  unsigned short* Wob  = (unsigned short*)p;  p += (size_t)2048 * 2048 * 2;
  unsigned short* QKV  = (unsigned short*)p;  p += (size_t)4096 * 2304 * 2;
  unsigned short* Vt   = (unsigned short*)p;  p += (size_t)2 * 128 * 2048 * 2;
  float*          Kmax = (float*)p;           p += 64;
  unsigned short* Ob   = xb;  // xb dead after gemm1

  cast_f32_bf16_k<<<8192, 256, 0, stream>>>(x, xb, 2097152);
  build_wcat_k<<<4608, 256, 0, stream>>>(Wq, Wk, Wv, bq, bk, bv, Wcat, bcat, Kmax);
  cast_f32_bf16_k<<<4096, 256, 0, stream>>>(Wo, Wob, 1048576);
  gemm_nt<0><<<dim3(18, 32), 256, 0, stream>>>(xb, Wcat, bcat, QKV, 4096, NQKV, 2048);
  transpose_v<<<dim3(32, 2), 256, 0, stream>>>(QKV, Vt);
  kmax_k<<<16, 256, 0, stream>>>(QKV, Kmax);
  mqa_attn<<<512, 256, 0, stream>>>(QKV, Vt, Kmax, Ob);
  gemm_nt<1><<<dim3(16, 32), 256, 0, stream>>>(Ob, Wob, bo, out, 4096, 2048, 2048);
}

// Round 7
// 215.436 us; speedup vs baseline: 1.1796x; 1.1796x over previous
//
#include <hip/hip_runtime.h>

// MQA: B=2, S=2048, HID=2048, H=16, D=128 (single KV head), causal.
// Pipeline: cast -> fused QKV NT-GEMM (bf16 MFMA) -> V transpose -> kmax ->
//           flash attention (32x32x16 MFMA, in-register P via cvt_pk+shfl,
//           balanced 512-block grid, dbuf swizzled LDS KV) -> out NT-GEMM.

#define S_LEN 2048
#define HID_  2048
#define D_    128
#define NQKV  2304   // 2048 Q + 128 K + 128 V columns

typedef __attribute__((ext_vector_type(8))) short bf16x8;
typedef __attribute__((ext_vector_type(4))) float f32x4;
typedef __attribute__((ext_vector_type(16))) float f32x16;

__device__ __forceinline__ unsigned short f2b(float f) {
  union { float f; unsigned int u; } a; a.f = f;
  unsigned int u = a.u;
  return (unsigned short)((u + 0x7fffu + ((u >> 16) & 1u)) >> 16);  // RNE
}

__device__ __forceinline__ float b2f(unsigned short s) {
  union { unsigned int u; float f; } a; a.u = ((unsigned int)s) << 16;
  return a.f;
}

__device__ __forceinline__ void load_lds16(const void* g, void* l) {
  __builtin_amdgcn_global_load_lds(
      (const __attribute__((address_space(1))) void*)g,
      (__attribute__((address_space(3))) void*)l, 16, 0, 0);
}

__device__ __forceinline__ f32x4 mfma16(bf16x8 a, bf16x8 b, f32x4 c) {
  return __builtin_amdgcn_mfma_f32_16x16x32_bf16(a, b, c, 0, 0, 0);
}

__device__ __forceinline__ f32x16 mfma32(bf16x8 a, bf16x8 b, f32x16 c) {
  return __builtin_amdgcn_mfma_f32_32x32x16_bf16(a, b, c, 0, 0, 0);
}

__device__ __forceinline__ unsigned int cvtpk(float lo, float hi) {
  unsigned int r;
  asm volatile("v_cvt_pk_bf16_f32 %0, %1, %2" : "=v"(r) : "v"(lo), "v"(hi));
  return r;
}

// ---------------- casts / packing ----------------

__global__ void cast_f32_bf16_k(const float* __restrict__ in,
                                unsigned short* __restrict__ out, int n4) {
  const int idx = blockIdx.x * 256 + threadIdx.x;
  if (idx < n4) {
    const float4 v = ((const float4*)in)[idx];
    ushort4 o;
    o.x = f2b(v.x); o.y = f2b(v.y); o.z = f2b(v.z); o.w = f2b(v.w);
    ((ushort4*)out)[idx] = o;
  }
}

__global__ void build_wcat_k(const float* __restrict__ Wq,
                             const float* __restrict__ Wk,
                             const float* __restrict__ Wv,
                             const float* __restrict__ bq,
                             const float* __restrict__ bk,
                             const float* __restrict__ bv,
                             unsigned short* __restrict__ Wcat,
                             float* __restrict__ bcat,
                             float* __restrict__ Kmax) {
  const int idx = blockIdx.x * 256 + threadIdx.x;
  const int i = idx * 4;
  const int row = i >> 11;
  const int col = i & 2047;
  const float* src;
  if (row < 2048)      src = Wq + (size_t)row * 2048 + col;
  else if (row < 2176) src = Wk + (size_t)(row - 2048) * 2048 + col;
  else                 src = Wv + (size_t)(row - 2176) * 2048 + col;
  const float4 v = *(const float4*)src;
  ushort4 o;
  o.x = f2b(v.x); o.y = f2b(v.y); o.z = f2b(v.z); o.w = f2b(v.w);
  *(ushort4*)(Wcat + i) = o;
  if (idx < NQKV)
    bcat[idx] = (idx < 2048) ? bq[idx] : (idx < 2176) ? bk[idx - 2048] : bv[idx - 2176];
  if (idx < 2) Kmax[idx] = 0.f;   // re-init every launch (runs before kmax_k)
}

// Vt[b][d][s] = QKV[b*S+s][2176+d] -- LDS-tiled transpose
__global__ __launch_bounds__(256)
void transpose_v(const unsigned short* __restrict__ QKV,
                 unsigned short* __restrict__ Vt) {
  __shared__ unsigned short tile[64][136];
  const int tid = threadIdx.x;
  const int s0  = blockIdx.x * 64;
  const int b   = blockIdx.y;
  const int row = tid >> 2;
  const int cb  = (tid & 3) * 32;
  const unsigned short* src = QKV + (size_t)(b * S_LEN + s0 + row) * NQKV + 2176 + cb;
#pragma unroll
  for (int i = 0; i < 4; ++i)
    *(bf16x8*)&tile[row][cb + i * 8] = *(const bf16x8*)(src + i * 8);
  __syncthreads();
  const int d  = tid >> 1;
  const int sc = (tid & 1) * 32;
  unsigned short* dst = Vt + ((size_t)b * D_ + d) * S_LEN + s0 + sc;
#pragma unroll
  for (int i = 0; i < 4; ++i) {
    bf16x8 vv;
#pragma unroll
    for (int e = 0; e < 8; ++e) vv[e] = tile[sc + i * 8 + e][d];
    *(bf16x8*)(dst + i * 8) = vv;
  }
}

// max_s ||k[b,s]||^2 -> Kmax[b] (as float bits via atomicMax on uint)
__global__ __launch_bounds__(256)
void kmax_k(const unsigned short* __restrict__ QKV, float* __restrict__ Kmax) {
  __shared__ float red[256];
  const int tid = threadIdx.x;
  const int b = blockIdx.x >> 3;
  const int s = (blockIdx.x & 7) * 256 + tid;
  const unsigned short* kp = QKV + (size_t)(b * S_LEN + s) * NQKV + 2048;
  float sum = 0.f;
#pragma unroll
  for (int i = 0; i < 16; ++i) {
    bf16x8 v = *(const bf16x8*)(kp + i * 8);
#pragma unroll
    for (int e = 0; e < 8; ++e) { const float f = b2f((unsigned short)v[e]); sum += f * f; }
  }
  red[tid] = sum;
  __syncthreads();
  for (int off = 128; off > 0; off >>= 1) {
    if (tid < off) red[tid] = fmaxf(red[tid], red[tid + off]);
    __syncthreads();
  }
  if (tid == 0) atomicMax((unsigned int*)(Kmax + b), __float_as_uint(red[0]));
}

// ---------------- NT GEMM (m97 structure, unchanged) ----------------

template <int OUT_F32>
__global__ __launch_bounds__(256)
void gemm_nt(const unsigned short* __restrict__ A,
             const unsigned short* __restrict__ Bm,
             const float* __restrict__ bias,
             void* __restrict__ Cv,
             int M, int N, int K) {
  __shared__ unsigned short As[128 * 32];
  __shared__ unsigned short Bs[128 * 32];
  const int tid  = threadIdx.x;
  const int lane = tid & 63;
  const int wv   = tid >> 6;
  const int wr   = wv >> 1, wc = wv & 1;
  const int g    = lane >> 4, r = lane & 15;
  const int m0   = blockIdx.y * 128;
  const int n0   = blockIdx.x * 128;

  const unsigned short* ga0 = A  + (size_t)(m0 + (tid >> 2)) * K + (tid & 3) * 8;
  const unsigned short* ga1 = ga0 + (size_t)64 * K;
  const unsigned short* gb0 = Bm + (size_t)(n0 + (tid >> 2)) * K + (tid & 3) * 8;
  const unsigned short* gb1 = gb0 + (size_t)64 * K;

  f32x4 acc[4][4] = {};

  for (int k0 = 0; k0 < K; k0 += 32) {
    __syncthreads();
    load_lds16(ga0 + k0, &As[tid * 8]);
    load_lds16(ga1 + k0, &As[2048 + tid * 8]);
    load_lds16(gb0 + k0, &Bs[tid * 8]);
    load_lds16(gb1 + k0, &Bs[2048 + tid * 8]);
    __syncthreads();
    bf16x8 af[4], bfr[4];
#pragma unroll
    for (int i = 0; i < 4; ++i)
      af[i] = *(const bf16x8*)&As[(wr * 64 + i * 16 + r) * 32 + g * 8];
#pragma unroll
    for (int i = 0; i < 4; ++i)
      bfr[i] = *(const bf16x8*)&Bs[(wc * 64 + i * 16 + r) * 32 + g * 8];
#pragma unroll
    for (int i = 0; i < 4; ++i)
#pragma unroll
      for (int j = 0; j < 4; ++j)
        acc[i][j] = mfma16(af[i], bfr[j], acc[i][j]);
  }

#pragma unroll
  for (int i = 0; i < 4; ++i) {
    const int row = m0 + wr * 64 + i * 16 + g * 4;
#pragma unroll
    for (int j = 0; j < 4; ++j) {
      const int col = n0 + wc * 64 + j * 16 + r;
      const float bb = bias[col];
#pragma unroll
      for (int e = 0; e < 4; ++e) {
        const float v = acc[i][j][e] + bb;
        if (OUT_F32) ((float*)Cv)[(size_t)(row + e) * N + col] = v;
        else ((unsigned short*)Cv)[(size_t)(row + e) * N + col] = f2b(v);
      }
    }
  }
}

// ---------------- flash attention (causal, MQA) ----------------
// 32x32x16 MFMA. Wave = 1 head x 32 q-rows (Q in registers, B-operand).
// Block = 4 waves (4 heads) x 32 q-rows; grid 512 = 2b x 4hq x 64qt with
// qt = (x<256)? x&31 : 63-(x&31) -> co-resident CU pair does 33 tiles.
// Swapped QK^T puts q in lane dim -> softmax is per-lane scalar; P goes to
// PV A-frags via v_cvt_pk_bf16_f32 + shfl_xor(32) (NO LDS round-trip).
// K: [64][256B] rows, slot ^= (row&15). V: 2 d-rows packed per 256B row,
// same XOR (both conflict-free). LDS 64KB -> 2 blocks/CU, dbuf prefetch.

__global__ __launch_bounds__(256, 2)
void mqa_attn(const unsigned short* __restrict__ QKV,
              const unsigned short* __restrict__ Vt,
              const float* __restrict__ Kmax,
              unsigned short* __restrict__ Ob) {
  __shared__ __align__(16) char Ks[2][64 * 256];
  __shared__ __align__(16) char Vs[2][64 * 256];

  const int tid  = threadIdx.x;
  const int lane = tid & 63;
  const int wv   = tid >> 6;           // 0..3
  const int ln   = lane & 31;
  const int hi   = lane >> 5;
  const int x    = blockIdx.x;
  const int lo   = x & 255;
  const int b    = lo >> 7;
  const int hq   = (lo >> 5) & 3;
  const int qtl  = lo & 31;
  const int qt   = (x < 256) ? qtl : 63 - qtl;
  const int h    = hq * 4 + wv;
  const int qw   = qt * 32;
  const int nt   = (qt >> 1) + 1;      // KV tiles of 64

  // Q fragments (B-operand): lane holds Q[q=qw+ln][d = ch*16 + hi*8 + e]
  bf16x8 qf[8];
  {
    const unsigned short* qp =
        QKV + (size_t)(b * S_LEN + qw + ln) * NQKV + h * D_ + hi * 8;
#pragma unroll
    for (int ch = 0; ch < 8; ++ch) qf[ch] = *(const bf16x8*)(qp + ch * 16);
  }

  // Cauchy-Schwarz bound (exp2 domain), lane-uniform in q=ln
  const float sscale = 0.08838834764831845f * 1.4426950408889634f;  // scale*log2e
  float qn2 = 0.f;
#pragma unroll
  for (int ch = 0; ch < 8; ++ch)
#pragma unroll
    for (int e = 0; e < 8; ++e) {
      const float qv = b2f((unsigned short)qf[ch][e]);
      qn2 += qv * qv;
    }
  qn2 += __shfl_xor(qn2, 32);
  const float m0c = sqrtf(qn2) * sqrtf(Kmax[b]) * sscale + 1.0f;

  const char* kbc = (const char*)(QKV + (size_t)(b * S_LEN) * NQKV + 2048);
  const char* vbc = (const char*)(Vt + (size_t)b * D_ * S_LEN);

  f32x16 acc[4] = {};
  float accl = 0.f;

  // ---- staging: K 1024 chunks (64 rows x 16 slots), V 1024 chunks ----
#define STAGE(bufi, t)                                                         \
  {                                                                            \
    const int kv0_ = (t) * 64;                                                 \
    _Pragma("unroll")                                                          \
    for (int i_ = 0; i_ < 4; ++i_) {                                           \
      const int ch_ = tid + 256 * i_;                                          \
      const int kr_ = ch_ >> 4;                                                \
      const int kg_ = (ch_ & 15) ^ (kr_ & 15);                                 \
      load_lds16(kbc + (size_t)(kv0_ + kr_) * (NQKV * 2) + kg_ * 16,           \
                 Ks[bufi] + ch_ * 16);                                         \
      const int vg_ = (ch_ & 15) ^ (kr_ & 15);                                 \
      const int vd_ = kr_ * 2 + (vg_ >> 3);                                    \
      load_lds16(vbc + (size_t)vd_ * (S_LEN * 2) + kv0_ * 2 + (vg_ & 7) * 16,  \
                 Vs[bufi] + ch_ * 16);                                         \
    }                                                                          \
  }

  STAGE(0, 0);
  int cur = 0;

  for (int t = 0; t < nt; ++t) {
    __syncthreads();                       // publishes buf[cur]
    if (t + 1 < nt) STAGE(cur ^ 1, t + 1); // prefetch overlaps compute

    const char* ksb = Ks[cur];
    const char* vsb = Vs[cur];
    const int kv0 = t * 64;
    const bool last = (t == nt - 1);
    const bool doUp = (kv0 + 32 <= qw + 31);
    cur ^= 1;

    // QK^T (swapped): S[kv][q]; A = K from LDS, B = Q regs
    f32x16 s0 = {}, s1 = {};
    __builtin_amdgcn_s_setprio(1);
#pragma unroll
    for (int ch = 0; ch < 8; ++ch) {
      const int slot0 = (2 * ch + hi) ^ (ln & 15);
      const bf16x8 kf0 = *(const bf16x8*)(ksb + ln * 256 + slot0 * 16);
      s0 = mfma32(kf0, qf[ch], s0);
      if (doUp) {
        const bf16x8 kf1 = *(const bf16x8*)(ksb + (32 + ln) * 256 + slot0 * 16);
        s1 = mfma32(kf1, qf[ch], s1);
      }
    }
    __builtin_amdgcn_s_setprio(0);

    // softmax (per-lane scalar; q = ln) + pack into PV A-frags, no LDS
    bf16x8 pa0, pa1, pa2, pa3;
    float p[16];

#define SOFTMAX(sv, kvtbase)                                                   \
    _Pragma("unroll")                                                          \
    for (int r = 0; r < 16; ++r) {                                             \
      float e = sv[r] * sscale - m0c;                                          \
      if (last) {                                                              \
        const int kva = (kvtbase) + (r & 3) + 8 * (r >> 2) + 4 * hi;           \
        e = (kva <= qw + ln) ? e : -__builtin_inff();                          \
      }                                                                        \
      const float pv_ = __builtin_amdgcn_exp2f(e);                             \
      p[r] = pv_; accl += pv_;                                                 \
    }

#define PACK2(fa, fb)                                                          \
    {                                                                          \
      const unsigned int A0 = cvtpk(p[0], p[1]),   A1 = cvtpk(p[2], p[3]);     \
      const unsigned int B0 = cvtpk(p[4], p[5]),   B1 = cvtpk(p[6], p[7]);     \
      const unsigned int C0 = cvtpk(p[8], p[9]),   C1 = cvtpk(p[10], p[11]);   \
      const unsigned int D0 = cvtpk(p[12], p[13]), D1 = cvtpk(p[14], p[15]);   \
      unsigned int X0 = hi ? A0 : B0, X1 = hi ? A1 : B1;                       \
      unsigned int Y0 = hi ? C0 : D0, Y1 = hi ? C1 : D1;                       \
      X0 = (unsigned int)__shfl_xor((int)X0, 32);                              \
      X1 = (unsigned int)__shfl_xor((int)X1, 32);                              \
      Y0 = (unsigned int)__shfl_xor((int)Y0, 32);                              \
      Y1 = (unsigned int)__shfl_xor((int)Y1, 32);                              \
      union { unsigned int w[4]; bf16x8 v; } ua, ub;                           \
      ua.w[0] = hi ? X0 : A0; ua.w[1] = hi ? X1 : A1;                          \
      ua.w[2] = hi ? B0 : X0; ua.w[3] = hi ? B1 : X1;                          \
      ub.w[0] = hi ? Y0 : C0; ub.w[1] = hi ? Y1 : C1;                          \
      ub.w[2] = hi ? D0 : Y0; ub.w[3] = hi ? D1 : Y1;                          \
      fa = ua.v; fb = ub.v;                                                    \
    }

    SOFTMAX(s0, kv0)
    PACK2(pa0, pa1)
    if (doUp) {
      SOFTMAX(s1, kv0 + 32)
      PACK2(pa2, pa3)
    }

    // PV: acc[dt] += P(32q x 64kv) * V(kv x 32d); B = V from LDS
    __builtin_amdgcn_s_setprio(1);
#pragma unroll
    for (int dt = 0; dt < 4; ++dt) {
      const int vrow = dt * 16 + (ln >> 1);
      const int gb   = (ln & 1) << 3;
      {
        const int sl = (gb + 0 + hi) ^ (vrow & 15);
        const bf16x8 vf = *(const bf16x8*)(vsb + vrow * 256 + sl * 16);
        acc[dt] = mfma32(pa0, vf, acc[dt]);
      }
      {
        const int sl = (gb + 2 + hi) ^ (vrow & 15);
        const bf16x8 vf = *(const bf16x8*)(vsb + vrow * 256 + sl * 16);
        acc[dt] = mfma32(pa1, vf, acc[dt]);
      }
      if (doUp) {
        {
          const int sl = (gb + 4 + hi) ^ (vrow & 15);
          const bf16x8 vf = *(const bf16x8*)(vsb + vrow * 256 + sl * 16);
          acc[dt] = mfma32(pa2, vf, acc[dt]);
        }
        {
          const int sl = (gb + 6 + hi) ^ (vrow & 15);
          const bf16x8 vf = *(const bf16x8*)(vsb + vrow * 256 + sl * 16);
          acc[dt] = mfma32(pa3, vf, acc[dt]);
        }
      }
    }
    __builtin_amdgcn_s_setprio(0);
#undef SOFTMAX
#undef PACK2
  }

  // epilogue: full row-sum, per-reg 1/l via shfl, store bf16
  const float lf = accl + __shfl_xor(accl, 32);
  const float linv = 1.0f / lf;
  unsigned short* ob = Ob + (size_t)(b * S_LEN + qw) * HID_ + h * D_ + ln;
#pragma unroll
  for (int r = 0; r < 16; ++r) {
    const int qr = (r & 3) + 8 * (r >> 2) + 4 * hi;
    const float li = __shfl(linv, qr);
#pragma unroll
    for (int dt = 0; dt < 4; ++dt)
      ob[(size_t)qr * HID_ + dt * 32] = f2b(acc[dt][r] * li);
  }
#undef STAGE
}

// ---------------- launcher ----------------

extern "C" void kernel_launch(void* const* d_in, const int* in_sizes, int n_in,
                              void* d_out, int out_size, void* d_ws, size_t ws_size,
                              hipStream_t stream) {
  (void)in_sizes; (void)n_in; (void)out_size; (void)ws_size;
  const float* x  = (const float*)d_in[0];
  const float* Wq = (const float*)d_in[2];
  const float* bq = (const float*)d_in[3];
  const float* Wk = (const float*)d_in[4];
  const float* bk = (const float*)d_in[5];
  const float* Wv = (const float*)d_in[6];
  const float* bv = (const float*)d_in[7];
  const float* Wo = (const float*)d_in[8];
  const float* bo = (const float*)d_in[9];
  float* out = (float*)d_out;

  char* p = (char*)d_ws;
  unsigned short* xb   = (unsigned short*)p;  p += (size_t)4096 * 2048 * 2;
  unsigned short* Wcat = (unsigned short*)p;  p += (size_t)2304 * 2048 * 2;
  float*          bcat = (float*)p;           p += 16384;
  unsigned short* Wob  = (unsigned short*)p;  p += (size_t)2048 * 2048 * 2;
  unsigned short* QKV  = (unsigned short*)p;  p += (size_t)4096 * 2304 * 2;
  unsigned short* Vt   = (unsigned short*)p;  p += (size_t)2 * 128 * 2048 * 2;
  float*          Kmax = (float*)p;           p += 64;
  unsigned short* Ob   = xb;  // xb dead after gemm1

  cast_f32_bf16_k<<<8192, 256, 0, stream>>>(x, xb, 2097152);
  build_wcat_k<<<4608, 256, 0, stream>>>(Wq, Wk, Wv, bq, bk, bv, Wcat, bcat, Kmax);
  cast_f32_bf16_k<<<4096, 256, 0, stream>>>(Wo, Wob, 1048576);
  gemm_nt<0><<<dim3(18, 32), 256, 0, stream>>>(xb, Wcat, bcat, QKV, 4096, NQKV, 2048);
  transpose_v<<<dim3(32, 2), 256, 0, stream>>>(QKV, Vt);
  kmax_k<<<16, 256, 0, stream>>>(QKV, Kmax);
  mqa_attn<<<512, 256, 0, stream>>>(QKV, Vt, Kmax, Ob);
  gemm_nt<1><<<dim3(16, 32), 256, 0, stream>>>(Ob, Wob, bo, out, 4096, 2048, 2048);
}

// Round 9
// 199.222 us; speedup vs baseline: 1.2756x; 1.0814x over previous
//
#include <hip/hip_runtime.h>

// MQA: B=2, S=2048, HID=2048, H=16, D=128 (single KV head), causal.
// Pipeline: cast -> fused QKV NT-GEMM (pipelined, counted-vmcnt) -> V
//           transpose -> kmax -> flash attention (32x32x16, in-register P)
//           -> out NT-GEMM (pipelined).

#define S_LEN 2048
#define HID_  2048
#define D_    128
#define NQKV  2304   // 2048 Q + 128 K + 128 V columns

typedef __attribute__((ext_vector_type(8))) short bf16x8;
typedef __attribute__((ext_vector_type(4))) float f32x4;
typedef __attribute__((ext_vector_type(16))) float f32x16;

__device__ __forceinline__ unsigned short f2b(float f) {
  union { float f; unsigned int u; } a; a.f = f;
  unsigned int u = a.u;
  return (unsigned short)((u + 0x7fffu + ((u >> 16) & 1u)) >> 16);  // RNE
}

__device__ __forceinline__ float b2f(unsigned short s) {
  union { unsigned int u; float f; } a; a.u = ((unsigned int)s) << 16;
  return a.f;
}

__device__ __forceinline__ void load_lds16(const void* g, void* l) {
  __builtin_amdgcn_global_load_lds(
      (const __attribute__((address_space(1))) void*)g,
      (__attribute__((address_space(3))) void*)l, 16, 0, 0);
}

__device__ __forceinline__ f32x4 mfma16(bf16x8 a, bf16x8 b, f32x4 c) {
  return __builtin_amdgcn_mfma_f32_16x16x32_bf16(a, b, c, 0, 0, 0);
}

__device__ __forceinline__ f32x16 mfma32(bf16x8 a, bf16x8 b, f32x16 c) {
  return __builtin_amdgcn_mfma_f32_32x32x16_bf16(a, b, c, 0, 0, 0);
}

__device__ __forceinline__ unsigned int cvtpk(float lo, float hi) {
  unsigned int r;
  asm volatile("v_cvt_pk_bf16_f32 %0, %1, %2" : "=v"(r) : "v"(lo), "v"(hi));
  return r;
}

// ---------------- casts / packing ----------------

__global__ void cast_f32_bf16_k(const float* __restrict__ in,
                                unsigned short* __restrict__ out, int n4) {
  const int idx = blockIdx.x * 256 + threadIdx.x;
  if (idx < n4) {
    const float4 v = ((const float4*)in)[idx];
    ushort4 o;
    o.x = f2b(v.x); o.y = f2b(v.y); o.z = f2b(v.z); o.w = f2b(v.w);
    ((ushort4*)out)[idx] = o;
  }
}

__global__ void build_wcat_k(const float* __restrict__ Wq,
                             const float* __restrict__ Wk,
                             const float* __restrict__ Wv,
                             const float* __restrict__ bq,
                             const float* __restrict__ bk,
                             const float* __restrict__ bv,
                             unsigned short* __restrict__ Wcat,
                             float* __restrict__ bcat,
                             float* __restrict__ Kmax) {
  const int idx = blockIdx.x * 256 + threadIdx.x;
  const int i = idx * 4;
  const int row = i >> 11;
  const int col = i & 2047;
  const float* src;
  if (row < 2048)      src = Wq + (size_t)row * 2048 + col;
  else if (row < 2176) src = Wk + (size_t)(row - 2048) * 2048 + col;
  else                 src = Wv + (size_t)(row - 2176) * 2048 + col;
  const float4 v = *(const float4*)src;
  ushort4 o;
  o.x = f2b(v.x); o.y = f2b(v.y); o.z = f2b(v.z); o.w = f2b(v.w);
  *(ushort4*)(Wcat + i) = o;
  if (idx < NQKV)
    bcat[idx] = (idx < 2048) ? bq[idx] : (idx < 2176) ? bk[idx - 2048] : bv[idx - 2176];
  if (idx < 2) Kmax[idx] = 0.f;   // re-init every launch (runs before kmax_k)
}

// Vt[b][d][s] = QKV[b*S+s][2176+d] -- LDS-tiled transpose
__global__ __launch_bounds__(256)
void transpose_v(const unsigned short* __restrict__ QKV,
                 unsigned short* __restrict__ Vt) {
  __shared__ unsigned short tile[64][136];
  const int tid = threadIdx.x;
  const int s0  = blockIdx.x * 64;
  const int b   = blockIdx.y;
  const int row = tid >> 2;
  const int cb  = (tid & 3) * 32;
  const unsigned short* src = QKV + (size_t)(b * S_LEN + s0 + row) * NQKV + 2176 + cb;
#pragma unroll
  for (int i = 0; i < 4; ++i)
    *(bf16x8*)&tile[row][cb + i * 8] = *(const bf16x8*)(src + i * 8);
  __syncthreads();
  const int d  = tid >> 1;
  const int sc = (tid & 1) * 32;
  unsigned short* dst = Vt + ((size_t)b * D_ + d) * S_LEN + s0 + sc;
#pragma unroll
  for (int i = 0; i < 4; ++i) {
    bf16x8 vv;
#pragma unroll
    for (int e = 0; e < 8; ++e) vv[e] = tile[sc + i * 8 + e][d];
    *(bf16x8*)(dst + i * 8) = vv;
  }
}

// max_s ||k[b,s]||^2 -> Kmax[b] (as float bits via atomicMax on uint)
__global__ __launch_bounds__(256)
void kmax_k(const unsigned short* __restrict__ QKV, float* __restrict__ Kmax) {
  __shared__ float red[256];
  const int tid = threadIdx.x;
  const int b = blockIdx.x >> 3;
  const int s = (blockIdx.x & 7) * 256 + tid;
  const unsigned short* kp = QKV + (size_t)(b * S_LEN + s) * NQKV + 2048;
  float sum = 0.f;
#pragma unroll
  for (int i = 0; i < 16; ++i) {
    bf16x8 v = *(const bf16x8*)(kp + i * 8);
#pragma unroll
    for (int e = 0; e < 8; ++e) { const float f = b2f((unsigned short)v[e]); sum += f * f; }
  }
  red[tid] = sum;
  __syncthreads();
  for (int off = 128; off > 0; off >>= 1) {
    if (tid < off) red[tid] = fmaxf(red[tid], red[tid + off]);
    __syncthreads();
  }
  if (tid == 0) atomicMax((unsigned int*)(Kmax + b), __float_as_uint(red[0]));
}

// ---------------- pipelined NT GEMM ----------------
// C[m,n] = sum_k A[m,k]*B[n,k] + bias[n].  BM=128, BN=64*NJ, BK=64, 8 waves
// (2M x 4N, per-wave 64 x 16NJ).  Triple-buffered LDS, prefetch distance 2,
// counted vmcnt (never 0 in steady state), raw s_barrier, slot-XOR swizzle
// via pre-swizzled global source (rule 21).  K must be a multiple of 128.

template <int OUT_F32, int NJ>
__global__ __launch_bounds__(512, 2)
void gemm_nt2(const unsigned short* __restrict__ A,
              const unsigned short* __restrict__ Bm,
              const float* __restrict__ bias,
              void* __restrict__ Cv,
              int N, int K) {
  constexpr int BN = 64 * NJ;
  __shared__ __align__(16) char As[3][128 * 128];   // [buf][row<<7 | slot*16]
  __shared__ __align__(16) char Bs[3][BN * 128];

  const int tid  = threadIdx.x;
  const int lane = tid & 63;
  const int wv   = tid >> 6;
  const int wr   = wv >> 2;        // 0..1
  const int wc   = wv & 3;         // 0..3
  const int g    = lane >> 4, r = lane & 15;

  const int nwg  = gridDim.x;
  const int bid  = blockIdx.x;
  const int sbid = (bid & 7) * (nwg >> 3) + (bid >> 3);   // XCD-chunked
  const int nx   = N / BN;
  const int m0   = (sbid / nx) * 128;
  const int n0   = (sbid % nx) * BN;
  const int NT   = K >> 6;

  const size_t Kb = (size_t)K * 2;
  const char* Ab = (const char*)A + (size_t)m0 * Kb;
  const char* Bb = (const char*)Bm + (size_t)n0 * Kb;

#define STAGE_A(bufi, t)                                                       \
  {                                                                            \
    const int kb_ = (t) * 128;                                                 \
    _Pragma("unroll")                                                          \
    for (int i_ = 0; i_ < 2; ++i_) {                                           \
      const int ch_ = tid + 512 * i_;                                          \
      const int rr_ = ch_ >> 3;                                                \
      const int sl_ = (ch_ & 7) ^ (rr_ & 7);                                   \
      load_lds16(Ab + (size_t)rr_ * Kb + kb_ + sl_ * 16, As[bufi] + ch_ * 16); \
    }                                                                          \
  }
#define STAGE_B(bufi, t)                                                       \
  {                                                                            \
    const int kb_ = (t) * 128;                                                 \
    _Pragma("unroll")                                                          \
    for (int i_ = 0; i_ < NJ; ++i_) {                                          \
      const int ch_ = tid + 512 * i_;                                          \
      const int rr_ = ch_ >> 3;                                                \
      const int sl_ = (ch_ & 7) ^ (rr_ & 7);                                   \
      load_lds16(Bb + (size_t)rr_ * Kb + kb_ + sl_ * 16, Bs[bufi] + ch_ * 16); \
    }                                                                          \
  }

  f32x4 acc[4][NJ] = {};
  const int s0 = ((g ^ (r & 7)) << 4);           // kk=0 slot byte
  const int s1 = (((4 | g) ^ (r & 7)) << 4);     // kk=1 slot byte

  STAGE_A(0, 0) STAGE_B(0, 0) STAGE_A(1, 1) STAGE_B(1, 1)

  // FIX (R8): publish buf0 before the t=0 reads. Without this, the first
  // K-tile is read from unwritten LDS (vmcnt tracks global_load_lds, and the
  // first in-loop vmcnt wait is only at the END of iteration 0).
  asm volatile("s_waitcnt vmcnt(%0)" :: "i"(NJ + 2) : "memory");
  __builtin_amdgcn_s_barrier();
  __builtin_amdgcn_sched_barrier(0);

  for (int t = 0; t < NT; ++t) {
    const char* as = As[t % 3];
    const char* bs = Bs[t % 3];
    const int nb = (t + 2) % 3;
    const bool pf = (t + 2 < NT);

    bf16x8 af[4], bfr[NJ];
    // ---- phase 0 (kk = 0) ----
#pragma unroll
    for (int i = 0; i < 4; ++i)
      af[i] = *(const bf16x8*)(as + ((wr * 64 + i * 16 + r) << 7) + s0);
#pragma unroll
    for (int j = 0; j < NJ; ++j)
      bfr[j] = *(const bf16x8*)(bs + ((wc * 16 * NJ + j * 16 + r) << 7) + s0);
    if (pf) STAGE_A(nb, t + 2)
    __builtin_amdgcn_s_barrier();
    __builtin_amdgcn_sched_barrier(0);
    asm volatile("s_waitcnt lgkmcnt(0)" ::: "memory");
    __builtin_amdgcn_sched_barrier(0);
    __builtin_amdgcn_s_setprio(1);
#pragma unroll
    for (int i = 0; i < 4; ++i)
#pragma unroll
      for (int j = 0; j < NJ; ++j)
        acc[i][j] = mfma16(af[i], bfr[j], acc[i][j]);
    __builtin_amdgcn_s_setprio(0);
    __builtin_amdgcn_sched_barrier(0);

    // ---- phase 1 (kk = 1) ----
#pragma unroll
    for (int i = 0; i < 4; ++i)
      af[i] = *(const bf16x8*)(as + ((wr * 64 + i * 16 + r) << 7) + s1);
#pragma unroll
    for (int j = 0; j < NJ; ++j)
      bfr[j] = *(const bf16x8*)(bs + ((wc * 16 * NJ + j * 16 + r) << 7) + s1);
    if (pf) STAGE_B(nb, t + 2)
    __builtin_amdgcn_s_barrier();
    __builtin_amdgcn_sched_barrier(0);
    asm volatile("s_waitcnt lgkmcnt(0)" ::: "memory");
    __builtin_amdgcn_sched_barrier(0);
    __builtin_amdgcn_s_setprio(1);
#pragma unroll
    for (int i = 0; i < 4; ++i)
#pragma unroll
      for (int j = 0; j < NJ; ++j)
        acc[i][j] = mfma16(af[i], bfr[j], acc[i][j]);
    __builtin_amdgcn_s_setprio(0);

    // ---- tile boundary: publish buf t+1 (counted vmcnt, never 0 mid-loop) --
    if (pf) { asm volatile("s_waitcnt vmcnt(%0)" :: "i"(NJ + 2) : "memory"); }
    else    { asm volatile("s_waitcnt vmcnt(0)" ::: "memory"); }
    __builtin_amdgcn_s_barrier();
    __builtin_amdgcn_sched_barrier(0);
  }

  // epilogue
#pragma unroll
  for (int i = 0; i < 4; ++i) {
    const int row = m0 + wr * 64 + i * 16 + g * 4;
#pragma unroll
    for (int j = 0; j < NJ; ++j) {
      const int col = n0 + wc * 16 * NJ + j * 16 + r;
      const float bb = bias[col];
#pragma unroll
      for (int e = 0; e < 4; ++e) {
        const float v = acc[i][j][e] + bb;
        if (OUT_F32) ((float*)Cv)[(size_t)(row + e) * N + col] = v;
        else ((unsigned short*)Cv)[(size_t)(row + e) * N + col] = f2b(v);
      }
    }
  }
#undef STAGE_A
#undef STAGE_B
}

// ---------------- flash attention (causal, MQA) ----------------
// 32x32x16 MFMA. Wave = 1 head x 32 q-rows (Q in registers, B-operand).
// Swapped QK^T -> per-lane scalar softmax -> P packed to PV A-frags via
// v_cvt_pk_bf16_f32 + shfl_xor(32) (no LDS round-trip). Swizzled dbuf KV.

__global__ __launch_bounds__(256, 2)
void mqa_attn(const unsigned short* __restrict__ QKV,
              const unsigned short* __restrict__ Vt,
              const float* __restrict__ Kmax,
              unsigned short* __restrict__ Ob) {
  __shared__ __align__(16) char Ks[2][64 * 256];
  __shared__ __align__(16) char Vs[2][64 * 256];

  const int tid  = threadIdx.x;
  const int lane = tid & 63;
  const int wv   = tid >> 6;           // 0..3
  const int ln   = lane & 31;
  const int hi   = lane >> 5;
  const int x    = blockIdx.x;
  const int lo   = x & 255;
  const int b    = lo >> 7;
  const int hq   = (lo >> 5) & 3;
  const int qtl  = lo & 31;
  const int qt   = (x < 256) ? qtl : 63 - qtl;
  const int h    = hq * 4 + wv;
  const int qw   = qt * 32;
  const int nt   = (qt >> 1) + 1;      // KV tiles of 64

  bf16x8 qf[8];
  {
    const unsigned short* qp =
        QKV + (size_t)(b * S_LEN + qw + ln) * NQKV + h * D_ + hi * 8;
#pragma unroll
    for (int ch = 0; ch < 8; ++ch) qf[ch] = *(const bf16x8*)(qp + ch * 16);
  }

  const float sscale = 0.08838834764831845f * 1.4426950408889634f;  // scale*log2e
  float qn2 = 0.f;
#pragma unroll
  for (int ch = 0; ch < 8; ++ch)
#pragma unroll
    for (int e = 0; e < 8; ++e) {
      const float qv = b2f((unsigned short)qf[ch][e]);
      qn2 += qv * qv;
    }
  qn2 += __shfl_xor(qn2, 32);
  const float m0c = sqrtf(qn2) * sqrtf(Kmax[b]) * sscale + 1.0f;

  const char* kbc = (const char*)(QKV + (size_t)(b * S_LEN) * NQKV + 2048);
  const char* vbc = (const char*)(Vt + (size_t)b * D_ * S_LEN);

  f32x16 acc[4] = {};
  float accl = 0.f;

#define STAGE(bufi, t)                                                         \
  {                                                                            \
    const int kv0_ = (t) * 64;                                                 \
    _Pragma("unroll")                                                          \
    for (int i_ = 0; i_ < 4; ++i_) {                                           \
      const int ch_ = tid + 256 * i_;                                          \
      const int kr_ = ch_ >> 4;                                                \
      const int kg_ = (ch_ & 15) ^ (kr_ & 15);                                 \
      load_lds16(kbc + (size_t)(kv0_ + kr_) * (NQKV * 2) + kg_ * 16,           \
                 Ks[bufi] + ch_ * 16);                                         \
      const int vg_ = (ch_ & 15) ^ (kr_ & 15);                                 \
      const int vd_ = kr_ * 2 + (vg_ >> 3);                                    \
      load_lds16(vbc + (size_t)vd_ * (S_LEN * 2) + kv0_ * 2 + (vg_ & 7) * 16,  \
                 Vs[bufi] + ch_ * 16);                                         \
    }                                                                          \
  }

  STAGE(0, 0);
  int cur = 0;

  for (int t = 0; t < nt; ++t) {
    __syncthreads();
    if (t + 1 < nt) STAGE(cur ^ 1, t + 1);

    const char* ksb = Ks[cur];
    const char* vsb = Vs[cur];
    const int kv0 = t * 64;
    const bool last = (t == nt - 1);
    const bool doUp = (kv0 + 32 <= qw + 31);
    cur ^= 1;

    f32x16 sA = {}, sB = {};
    __builtin_amdgcn_s_setprio(1);
#pragma unroll
    for (int ch = 0; ch < 8; ++ch) {
      const int slot0 = (2 * ch + hi) ^ (ln & 15);
      const bf16x8 kf0 = *(const bf16x8*)(ksb + ln * 256 + slot0 * 16);
      sA = mfma32(kf0, qf[ch], sA);
      if (doUp) {
        const bf16x8 kf1 = *(const bf16x8*)(ksb + (32 + ln) * 256 + slot0 * 16);
        sB = mfma32(kf1, qf[ch], sB);
      }
    }
    __builtin_amdgcn_s_setprio(0);

    bf16x8 pa0, pa1, pa2, pa3;
    float p[16];

#define SOFTMAX(sv, kvtbase)                                                   \
    _Pragma("unroll")                                                          \
    for (int rr = 0; rr < 16; ++rr) {                                          \
      float e = sv[rr] * sscale - m0c;                                         \
      if (last) {                                                              \
        const int kva = (kvtbase) + (rr & 3) + 8 * (rr >> 2) + 4 * hi;         \
        e = (kva <= qw + ln) ? e : -__builtin_inff();                          \
      }                                                                        \
      const float pv_ = __builtin_amdgcn_exp2f(e);                             \
      p[rr] = pv_; accl += pv_;                                                \
    }

#define PACK2(fa, fb)                                                          \
    {                                                                          \
      const unsigned int A0 = cvtpk(p[0], p[1]),   A1 = cvtpk(p[2], p[3]);     \
      const unsigned int B0 = cvtpk(p[4], p[5]),   B1 = cvtpk(p[6], p[7]);     \
      const unsigned int C0 = cvtpk(p[8], p[9]),   C1 = cvtpk(p[10], p[11]);   \
      const unsigned int D0 = cvtpk(p[12], p[13]), D1 = cvtpk(p[14], p[15]);   \
      unsigned int X0 = hi ? A0 : B0, X1 = hi ? A1 : B1;                       \
      unsigned int Y0 = hi ? C0 : D0, Y1 = hi ? C1 : D1;                       \
      X0 = (unsigned int)__shfl_xor((int)X0, 32);                              \
      X1 = (unsigned int)__shfl_xor((int)X1, 32);                              \
      Y0 = (unsigned int)__shfl_xor((int)Y0, 32);                              \
      Y1 = (unsigned int)__shfl_xor((int)Y1, 32);                              \
      union { unsigned int w[4]; bf16x8 v; } ua, ub;                           \
      ua.w[0] = hi ? X0 : A0; ua.w[1] = hi ? X1 : A1;                          \
      ua.w[2] = hi ? B0 : X0; ua.w[3] = hi ? B1 : X1;                          \
      ub.w[0] = hi ? Y0 : C0; ub.w[1] = hi ? Y1 : C1;                          \
      ub.w[2] = hi ? D0 : Y0; ub.w[3] = hi ? D1 : Y1;                          \
      fa = ua.v; fb = ub.v;                                                    \
    }

    SOFTMAX(sA, kv0)
    PACK2(pa0, pa1)
    if (doUp) {
      SOFTMAX(sB, kv0 + 32)
      PACK2(pa2, pa3)
    }

    __builtin_amdgcn_s_setprio(1);
#pragma unroll
    for (int dt = 0; dt < 4; ++dt) {
      const int vrow = dt * 16 + (ln >> 1);
      const int gb   = (ln & 1) << 3;
      {
        const int sl = (gb + 0 + hi) ^ (vrow & 15);
        const bf16x8 vf = *(const bf16x8*)(vsb + vrow * 256 + sl * 16);
        acc[dt] = mfma32(pa0, vf, acc[dt]);
      }
      {
        const int sl = (gb + 2 + hi) ^ (vrow & 15);
        const bf16x8 vf = *(const bf16x8*)(vsb + vrow * 256 + sl * 16);
        acc[dt] = mfma32(pa1, vf, acc[dt]);
      }
      if (doUp) {
        {
          const int sl = (gb + 4 + hi) ^ (vrow & 15);
          const bf16x8 vf = *(const bf16x8*)(vsb + vrow * 256 + sl * 16);
          acc[dt] = mfma32(pa2, vf, acc[dt]);
        }
        {
          const int sl = (gb + 6 + hi) ^ (vrow & 15);
          const bf16x8 vf = *(const bf16x8*)(vsb + vrow * 256 + sl * 16);
          acc[dt] = mfma32(pa3, vf, acc[dt]);
        }
      }
    }
    __builtin_amdgcn_s_setprio(0);
#undef SOFTMAX
#undef PACK2
  }

  const float lf = accl + __shfl_xor(accl, 32);
  const float linv = 1.0f / lf;
  unsigned short* ob = Ob + (size_t)(b * S_LEN + qw) * HID_ + h * D_ + ln;
#pragma unroll
  for (int rr = 0; rr < 16; ++rr) {
    const int qr = (rr & 3) + 8 * (rr >> 2) + 4 * hi;
    const float li = __shfl(linv, qr);
#pragma unroll
    for (int dt = 0; dt < 4; ++dt)
      ob[(size_t)qr * HID_ + dt * 32] = f2b(acc[dt][rr] * li);
  }
#undef STAGE
}

// ---------------- launcher ----------------

extern "C" void kernel_launch(void* const* d_in, const int* in_sizes, int n_in,
                              void* d_out, int out_size, void* d_ws, size_t ws_size,
                              hipStream_t stream) {
  (void)in_sizes; (void)n_in; (void)out_size; (void)ws_size;
  const float* x  = (const float*)d_in[0];
  const float* Wq = (const float*)d_in[2];
  const float* bq = (const float*)d_in[3];
  const float* Wk = (const float*)d_in[4];
  const float* bk = (const float*)d_in[5];
  const float* Wv = (const float*)d_in[6];
  const float* bv = (const float*)d_in[7];
  const float* Wo = (const float*)d_in[8];
  const float* bo = (const float*)d_in[9];
  float* out = (float*)d_out;

  char* p = (char*)d_ws;
  unsigned short* xb   = (unsigned short*)p;  p += (size_t)4096 * 2048 * 2;
  unsigned short* Wcat = (unsigned short*)p;  p += (size_t)2304 * 2048 * 2;
  float*          bcat = (float*)p;           p += 16384;
  unsigned short* Wob  = (unsigned short*)p;  p += (size_t)2048 * 2048 * 2;
  unsigned short* QKV  = (unsigned short*)p;  p += (size_t)4096 * 2304 * 2;
  unsigned short* Vt   = (unsigned short*)p;  p += (size_t)2 * 128 * 2048 * 2;
  float*          Kmax = (float*)p;           p += 64;
  unsigned short* Ob   = xb;  // xb dead after gemm1

  cast_f32_bf16_k<<<8192, 256, 0, stream>>>(x, xb, 2097152);
  build_wcat_k<<<4608, 256, 0, stream>>>(Wq, Wk, Wv, bq, bk, bv, Wcat, bcat, Kmax);
  cast_f32_bf16_k<<<4096, 256, 0, stream>>>(Wo, Wob, 1048576);
  gemm_nt2<0, 3><<<384, 512, 0, stream>>>(xb, Wcat, bcat, QKV, 2304, 2048);
  transpose_v<<<dim3(32, 2), 256, 0, stream>>>(QKV, Vt);
  kmax_k<<<16, 256, 0, stream>>>(QKV, Kmax);
  mqa_attn<<<512, 256, 0, stream>>>(QKV, Vt, Kmax, Ob);
  gemm_nt2<1, 4><<<256, 512, 0, stream>>>(Ob, Wob, bo, out, 2048, 2048);
}